// Round 10
// baseline (70.781 us; speedup 1.0000x reference)
//
#include <hip/hip_runtime.h>

#define B_ 4
#define C_ 128
#define N_ 4096
#define LOG2E 1.44269504088896340736f
#define KB_PER_B (C_ * N_ * 2)          // 1 MiB per batch for kQ / vQ

typedef __bf16 bf16x8 __attribute__((ext_vector_type(8)));
typedef __bf16 bf16x4 __attribute__((ext_vector_type(4)));
typedef float  f32x16 __attribute__((ext_vector_type(16)));
typedef int    i32x4  __attribute__((ext_vector_type(4)));

// 16B global -> LDS DMA. LDS dest = wave-uniform base + lane*16.
static __device__ __forceinline__ void stage16(const void* g_lane, char* lds_base, int lane16) {
#if __has_builtin(__builtin_amdgcn_global_load_lds)
    __builtin_amdgcn_global_load_lds(
        (const __attribute__((address_space(1))) void*)g_lane,
        (__attribute__((address_space(3))) void*)lds_base, 16, 0, 0);
    (void)lane16;
#else
    *(i32x4*)(lds_base + lane16) = *(const i32x4*)g_lane;
#endif
}

// ---------------- projection: q/k/v = W @ x + b (1x1 conv) -------------
// qT [B][N][C] bf16 (q scaled by log2e).
// kQ [B][tile64][j 64][chunk16B ^ (j&15)]          (16 KB / 64-key tile)
// vQ [B][tile64][R=c>>1 64][chunk16B ^ (R&15)]     (16 KB / 64-key tile)
//    chunkIdx = (c&1)*8 + 2m + hk; within-chunk M2 key order.
__global__ __launch_bounds__(256) void proj_kernel(
    const float* __restrict__ x,
    const float* __restrict__ Wq, const float* __restrict__ bq,
    const float* __restrict__ Wk, const float* __restrict__ bk,
    const float* __restrict__ Wv, const float* __restrict__ bv,
    unsigned short* __restrict__ qT, char* __restrict__ kQ,
    char* __restrict__ vQ)
{
    __shared__ __align__(16) char wlds[32768];   // W bf16, swizzled rows (256B)

    const int tid  = threadIdx.x;
    const int wave = tid >> 6;
    const int lane = tid & 63;
    const int col  = lane & 31;
    const int h    = lane >> 5;

    const int jw  = blockIdx.x * 4 + wave;   // 0..1535 = mat*512 + b*128 + nb
    const int mat = jw >> 9;                 // uniform per WG
    const int rem = jw & 511;
    const int b   = rem >> 7;
    const int nb  = rem & 127;
    const int n   = nb * 32 + col;

    const float* W    = (mat == 0) ? Wq : (mat == 1) ? Wk : Wv;
    const float* bias = (mat == 0) ? bq : (mat == 1) ? bk : bv;
    const float  scale = (mat == 0) ? LOG2E : 1.0f;

    #pragma unroll
    for (int k = 0; k < 16; ++k) {
        const int q = tid + k * 256;          // quad index, 4 floats each
        const int o = q >> 5;                 // W row (output channel)
        const int g = q & 31;                 // 8B granule within row
        float4 w = *((const float4*)W + q);
        bf16x4 d;
        d[0] = (__bf16)(w.x * scale); d[1] = (__bf16)(w.y * scale);
        d[2] = (__bf16)(w.z * scale); d[3] = (__bf16)(w.w * scale);
        *(bf16x4*)(wlds + o * 256 + ((((g >> 1) ^ (o & 15)) << 4) | ((g & 1) * 8))) = d;
    }
    __syncthreads();

    bf16x8 xf[8];
    const float* xcol = x + (size_t)b * C_ * N_ + n;
    #pragma unroll
    for (int ch = 0; ch < 8; ++ch) {
        const int c0 = ch * 16 + 8 * h;
        bf16x8 v;
        #pragma unroll
        for (int e = 0; e < 8; ++e) v[e] = (__bf16)xcol[(size_t)(c0 + e) * N_];
        xf[ch] = v;
    }

    f32x16 acc[4];
    #pragma unroll
    for (int ob = 0; ob < 4; ++ob)
        #pragma unroll
        for (int rr = 0; rr < 16; ++rr) acc[ob][rr] = 0.0f;

    #pragma unroll
    for (int ch = 0; ch < 8; ++ch) {
        #pragma unroll
        for (int ob = 0; ob < 4; ++ob) {
            const char* wrow = wlds + (ob * 32 + col) * 256;
            bf16x8 wf = __builtin_bit_cast(bf16x8,
                *(const i32x4*)(wrow + (((ch * 2 + h) ^ (col & 15)) << 4)));
            acc[ob] = __builtin_amdgcn_mfma_f32_32x32x16_bf16(
                wf, xf[ch], acc[ob], 0, 0, 0);
        }
    }

    if (mat == 0) {
        unsigned short* dst = qT + (size_t)(b * N_ + n) * C_;
        #pragma unroll
        for (int ob = 0; ob < 4; ++ob) {
            #pragma unroll
            for (int qd = 0; qd < 4; ++qd) {
                const int obase = ob * 32 + 8 * qd + 4 * h;
                bf16x4 d;
                d[0] = (__bf16)(acc[ob][4 * qd + 0] + bias[obase + 0] * scale);
                d[1] = (__bf16)(acc[ob][4 * qd + 1] + bias[obase + 1] * scale);
                d[2] = (__bf16)(acc[ob][4 * qd + 2] + bias[obase + 2] * scale);
                d[3] = (__bf16)(acc[ob][4 * qd + 3] + bias[obase + 3] * scale);
                *(bf16x4*)(dst + obase) = d;
            }
        }
    } else if (mat == 1) {
        const int kt = (nb & 1) * 32 + col;               // key within 64-tile
        char* dst = kQ + (size_t)b * KB_PER_B + (size_t)(nb >> 1) * 16384 + kt * 256;
        const int kx = kt & 15;
        #pragma unroll
        for (int ob = 0; ob < 4; ++ob) {
            #pragma unroll
            for (int qd = 0; qd < 4; ++qd) {
                const int obase = ob * 32 + 8 * qd + 4 * h;
                bf16x4 d;
                d[0] = (__bf16)(acc[ob][4 * qd + 0] + bias[obase + 0]);
                d[1] = (__bf16)(acc[ob][4 * qd + 1] + bias[obase + 1]);
                d[2] = (__bf16)(acc[ob][4 * qd + 2] + bias[obase + 2]);
                d[3] = (__bf16)(acc[ob][4 * qd + 3] + bias[obase + 3]);
                *(bf16x4*)(dst + ((((ob * 4 + qd) ^ kx) << 4) | (8 * h))) = d;
            }
        }
    } else {
        char* dst = vQ + (size_t)b * KB_PER_B + (size_t)(nb >> 1) * 16384;
        const int kt  = (nb & 1) * 32 + col;
        const int m   = kt >> 4;
        const int w16 = kt & 15;
        const int hk  = (w16 >> 2) & 1;
        const int pos = (w16 & 3) | (((w16 >> 3) & 1) << 2);   // M2 element index
        #pragma unroll
        for (int ob = 0; ob < 4; ++ob) {
            #pragma unroll
            for (int rr = 0; rr < 16; ++rr) {
                const int o = ob * 32 + (rr & 3) + 8 * (rr >> 2) + 4 * h;
                const int R = o >> 1;
                const int cidx = (o & 1) * 8 + 2 * m + hk;
                *(unsigned short*)(dst + R * 256 + (((cidx ^ (R & 15)) << 4)) + pos * 2) =
                    __builtin_bit_cast(unsigned short,
                                       (__bf16)(acc[ob][rr] + bias[o]));
            }
        }
    }
}

// ---------------- flash attention over N/NS keys per WG ----------------
// grid = B * (N/128) * NS WGs x 256 thr, 3 WG/CU target (48 KB LDS, <=170 reg).
// 4 waves = 4 q-blocks (128 q) share one 64-key tile stream.
// K double-buffered, V single-buffered (2 cheap barriers/tile).
// FIXED-SHIFT softmax: p = exp2(e); l via lane-local VALU sum.
template<int NS>
__global__ __launch_bounds__(256, 3) void attn_kernel(
    const unsigned short* __restrict__ qT,
    const char* __restrict__ kQ,
    const char* __restrict__ vQ,
    unsigned short* __restrict__ pO,  // [NS][B][C][N] bf16 (un-normalized)
    float* __restrict__ lG)           // [NS][B][N] denominators
{
    __shared__ __align__(16) char smem[49152];   // K0 16K | K1 16K | V 16K

    const int tid  = threadIdx.x;
    const int w    = tid >> 6;
    const int lane = tid & 63;
    const int l31  = lane & 31;
    const int h    = lane >> 5;

    const int orig = blockIdx.x;
    const int b    = (orig & 7) >> 1;                  // XCD-pair per batch
    const int idx  = ((orig >> 3) << 1) | (orig & 1);
    const int part = idx % NS;
    const int qg   = idx / NS;                         // 0..31
    const int i0   = qg * 128 + w * 32;

    const int NT = N_ / (NS * 64);                     // 64-key tiles per WG
    const char* kq0 = kQ + (size_t)b * KB_PER_B + (size_t)(part * NT) * 16384;
    const char* vq0 = vQ + (size_t)b * KB_PER_B + (size_t)(part * NT) * 16384;
    char* vbuf = smem + 32768;

    // Q fragments: element e of chunk ch <-> c = ch*16 + 8h + e
    bf16x8 qf[8];
    {
        const unsigned short* qrow = qT + (size_t)(b * N_ + i0 + l31) * C_;
        #pragma unroll
        for (int ch = 0; ch < 8; ++ch)
            qf[ch] = __builtin_bit_cast(bf16x8, *(const i32x4*)(qrow + ch * 16 + 8 * h));
    }

    f32x16 accO[4];
    #pragma unroll
    for (int cb = 0; cb < 4; ++cb)
        #pragma unroll
        for (int rr = 0; rr < 16; ++rr) accO[cb][rr] = 0.0f;
    float l_run = 0.0f;

    // staging: each wave copies 4 KB of a 16 KB tile image
    const int lane16 = lane * 16;
    auto stageK = [&](int t, char* kd) {
        const char* g = kq0 + (size_t)t * 16384 + w * 4096 + lane16;
        char* d = kd + w * 4096;
        #pragma unroll
        for (int u = 0; u < 4; ++u)
            stage16(g + u * 1024, d + u * 1024, lane16);
    };
    auto stageV = [&](int t) {
        const char* g = vq0 + (size_t)t * 16384 + w * 4096 + lane16;
        char* d = vbuf + w * 4096;
        #pragma unroll
        for (int u = 0; u < 4; ++u)
            stage16(g + u * 1024, d + u * 1024, lane16);
    };

    stageK(0, smem);
    __syncthreads();                  // K(0) ready
    int cur = 0;

    #pragma unroll 1
    for (int t = 0; t < NT; ++t) {
        char* kb = smem + cur * 16384;
        stageV(t);                                        // V(t) -> vbuf
        if (t + 1 < NT) stageK(t + 1, smem + (cur ^ 1) * 16384);

        // ---- E^T[j][i] = sum_c K[c,j] Q[c,i], j = row | row+32 ----
        f32x16 e0, e1;
        #pragma unroll
        for (int rr = 0; rr < 16; ++rr) { e0[rr] = 0.0f; e1[rr] = 0.0f; }
        {
            const char* kr0 = kb + l31 * 256;
            const int   kx  = l31 & 15;
            __builtin_amdgcn_s_setprio(1);
            #pragma unroll
            for (int ch = 0; ch < 8; ++ch) {
                const int off = ((2 * ch + h) ^ kx) << 4;
                bf16x8 k0 = __builtin_bit_cast(bf16x8, *(const i32x4*)(kr0 + off));
                e0 = __builtin_amdgcn_mfma_f32_32x32x16_bf16(k0, qf[ch], e0, 0, 0, 0);
                bf16x8 k1 = __builtin_bit_cast(bf16x8, *(const i32x4*)(kr0 + 8192 + off));
                e1 = __builtin_amdgcn_mfma_f32_32x32x16_bf16(k1, qf[ch], e1, 0, 0, 0);
            }
            __builtin_amdgcn_s_setprio(0);
        }

        // ---- fixed-shift softmax numerators: p = exp2(e) ----
        #pragma unroll
        for (int rr = 0; rr < 16; ++rr) {
            e0[rr] = exp2f(e0[rr]);
            e1[rr] = exp2f(e1[rr]);
        }

        // ---- lane-local denominator sum (32 adds, VALU) ----
        float lsum = 0.0f;
        #pragma unroll
        for (int rr = 0; rr < 16; ++rr) lsum += e0[rr] + e1[rr];
        l_run += lsum;

        // pack P: frag m element e <-> key 16m + (e&3) + 4h + 8*(e>>2)
        bf16x8 pf[4];
        #pragma unroll
        for (int m = 0; m < 4; ++m) {
            bf16x8 p;
            #pragma unroll
            for (int e = 0; e < 8; ++e)
                p[e] = (__bf16)((m < 2) ? e0[(m & 1) * 8 + e] : e1[(m & 1) * 8 + e]);
            pf[m] = p;
        }

        __syncthreads();              // V(t) visible (drains DMA; K(t+1) too)

        // ---- accO += V P ----
        {
            const int rsw = l31 >> 1;          // (R & 15)
            const int ci  = (l31 & 1) * 8;
            __builtin_amdgcn_s_setprio(1);
            #pragma unroll
            for (int cb = 0; cb < 4; ++cb) {
                const char* vrow = vbuf + (cb * 16 + (l31 >> 1)) * 256;
                #pragma unroll
                for (int m = 0; m < 4; ++m) {
                    bf16x8 vf = __builtin_bit_cast(bf16x8,
                        *(const i32x4*)(vrow + (((ci + 2 * m + h) ^ rsw) << 4)));
                    accO[cb] = __builtin_amdgcn_mfma_f32_32x32x16_bf16(
                        vf, pf[m], accO[cb], 0, 0, 0);
                }
            }
            __builtin_amdgcn_s_setprio(0);
        }

        __syncthreads();              // PV reads done -> vbuf & old K free
        cur ^= 1;
    }

    // ---- epilogue: un-normalized partial O (bf16) + denominator ----
    l_run += __shfl_xor(l_run, 32, 64);        // combine the two h halves
    if (h == 0)
        lG[((size_t)part * B_ + b) * N_ + i0 + l31] = l_run;

    unsigned short* pOq = pO + ((size_t)part * B_ + b) * C_ * N_;
    #pragma unroll
    for (int cb = 0; cb < 4; ++cb) {
        #pragma unroll
        for (int rr = 0; rr < 16; ++rr) {
            const int c = cb * 32 + (rr & 3) + 8 * (rr >> 2) + 4 * h;
            pOq[(size_t)c * N_ + i0 + l31] =
                __builtin_bit_cast(unsigned short, (__bf16)accO[cb][rr]);
        }
    }
}

// ---------------- merge NS key-range partials + residual ----------------
// Same fixed shift everywhere => merge is a plain sum.
template<int NS>
__global__ __launch_bounds__(256) void merge_kernel(
    const float* __restrict__ x,
    const unsigned short* __restrict__ pO,   // [NS][B][C][N] bf16
    const float* __restrict__ lG,            // [NS][B][N]
    float* __restrict__ out)
{
    const int idx = blockIdx.x * 256 + threadIdx.x;   // over B*C*N/4
    const int nq  = idx & (N_ / 4 - 1);
    const int bc  = idx >> 10;                        // b*C + c
    const int b   = bc >> 7;
    const size_t off = (size_t)bc * N_ + nq * 4;

    float4 xv = *(const float4*)(x + off);

    float num[4] = {0, 0, 0, 0}, den[4] = {0, 0, 0, 0};
    #pragma unroll
    for (int q = 0; q < NS; ++q) {
        bf16x4 r = *(const bf16x4*)(pO + (size_t)q * B_ * C_ * N_ + off);
        const float* lp = lG + ((size_t)q * B_ + b) * N_ + nq * 4;
        #pragma unroll
        for (int j = 0; j < 4; ++j) {
            num[j] += (float)r[j];
            den[j] += lp[j];
        }
    }
    float4 ov;
    ov.x = xv.x + num[0] / den[0];
    ov.y = xv.y + num[1] / den[1];
    ov.z = xv.z + num[2] / den[2];
    ov.w = xv.w + num[3] / den[3];
    *(float4*)(out + off) = ov;
}

extern "C" void kernel_launch(void* const* d_in, const int* in_sizes, int n_in,
                              void* d_out, int out_size, void* d_ws, size_t ws_size,
                              hipStream_t stream)
{
    const float* x  = (const float*)d_in[0];
    const float* Wq = (const float*)d_in[1];
    const float* bq = (const float*)d_in[2];
    const float* Wk = (const float*)d_in[3];
    const float* bk = (const float*)d_in[4];
    const float* Wv = (const float*)d_in[5];
    const float* bv = (const float*)d_in[6];
    float* out = (float*)d_out;

    unsigned short* qT = (unsigned short*)d_ws;              // 4 MiB
    char* kQ = (char*)(qT + (size_t)B_ * N_ * C_);           // 4 MiB
    char* vQ = kQ + (size_t)B_ * KB_PER_B;                   // 4 MiB
    unsigned short* pO = (unsigned short*)(vQ + (size_t)B_ * KB_PER_B);

    const size_t slotO = (size_t)B_ * C_ * N_;               // bf16 elems / slot
    const size_t slotL = (size_t)B_ * N_;                    // floats / slot
    const size_t base  = 3ull * B_ * N_ * C_ * 2;
    const size_t need8 = base + 8 * (slotO * 2 + slotL * 4);
    const size_t need4 = base + 4 * (slotO * 2 + slotL * 4);
    const int nMerge = (B_ * C_ * N_ / 4) / 256;

    proj_kernel<<<384, 256, 0, stream>>>(x, Wq, bq, Wk, bk, Wv, bv, qT, kQ, vQ);

    if (ws_size >= need8) {
        float* lG = (float*)(pO + 8 * slotO);
        attn_kernel<8><<<B_ * (N_ / 128) * 8, 256, 0, stream>>>(qT, kQ, vQ, pO, lG);
        merge_kernel<8><<<nMerge, 256, 0, stream>>>(x, pO, lG, out);
    } else if (ws_size >= need4) {
        float* lG = (float*)(pO + 4 * slotO);
        attn_kernel<4><<<B_ * (N_ / 128) * 4, 256, 0, stream>>>(qT, kQ, vQ, pO, lG);
        merge_kernel<4><<<nMerge, 256, 0, stream>>>(x, pO, lG, out);
    } else {
        float* lG = (float*)(pO + 2 * slotO);
        attn_kernel<2><<<B_ * (N_ / 128) * 2, 256, 0, stream>>>(qT, kQ, vQ, pO, lG);
        merge_kernel<2><<<nMerge, 256, 0, stream>>>(x, pO, lG, out);
    }
}

// Round 11
// 66.728 us; speedup vs baseline: 1.0607x; 1.0607x over previous
//
#include <hip/hip_runtime.h>

#define B_ 4
#define C_ 128
#define N_ 4096
#define LOG2E 1.44269504088896340736f
#define KB_PER_B (C_ * N_ * 2)          // 1 MiB per batch for kQ / vQ

typedef __bf16 bf16x8 __attribute__((ext_vector_type(8)));
typedef __bf16 bf16x4 __attribute__((ext_vector_type(4)));
typedef float  f32x16 __attribute__((ext_vector_type(16)));
typedef int    i32x4  __attribute__((ext_vector_type(4)));

// 16B global -> LDS DMA. LDS dest = wave-uniform base + lane*16.
static __device__ __forceinline__ void stage16(const void* g_lane, char* lds_base, int lane16) {
#if __has_builtin(__builtin_amdgcn_global_load_lds)
    __builtin_amdgcn_global_load_lds(
        (const __attribute__((address_space(1))) void*)g_lane,
        (__attribute__((address_space(3))) void*)lds_base, 16, 0, 0);
    (void)lane16;
#else
    *(i32x4*)(lds_base + lane16) = *(const i32x4*)g_lane;
#endif
}

// ---------------- projection: q/k/v = W @ x + b (1x1 conv) -------------
// qT [B][N][C] bf16 (q scaled by log2e).
// kQ [B][tile64][j 64][chunk16B ^ (j&15)]          (16 KB / 64-key tile)
// vQ [B][tile64][R=c>>1 64][chunk16B ^ (R&15)]     (16 KB / 64-key tile)
//    chunkIdx = (c&1)*8 + 2m + hk; within-chunk M2 key order.
__global__ __launch_bounds__(256) void proj_kernel(
    const float* __restrict__ x,
    const float* __restrict__ Wq, const float* __restrict__ bq,
    const float* __restrict__ Wk, const float* __restrict__ bk,
    const float* __restrict__ Wv, const float* __restrict__ bv,
    unsigned short* __restrict__ qT, char* __restrict__ kQ,
    char* __restrict__ vQ)
{
    __shared__ __align__(16) char wlds[32768];   // W bf16, swizzled rows (256B)

    const int tid  = threadIdx.x;
    const int wave = tid >> 6;
    const int lane = tid & 63;
    const int col  = lane & 31;
    const int h    = lane >> 5;

    const int jw  = blockIdx.x * 4 + wave;   // 0..1535 = mat*512 + b*128 + nb
    const int mat = jw >> 9;                 // uniform per WG
    const int rem = jw & 511;
    const int b   = rem >> 7;
    const int nb  = rem & 127;
    const int n   = nb * 32 + col;

    const float* W    = (mat == 0) ? Wq : (mat == 1) ? Wk : Wv;
    const float* bias = (mat == 0) ? bq : (mat == 1) ? bk : bv;
    const float  scale = (mat == 0) ? LOG2E : 1.0f;

    #pragma unroll
    for (int k = 0; k < 16; ++k) {
        const int q = tid + k * 256;          // quad index, 4 floats each
        const int o = q >> 5;                 // W row (output channel)
        const int g = q & 31;                 // 8B granule within row
        float4 w = *((const float4*)W + q);
        bf16x4 d;
        d[0] = (__bf16)(w.x * scale); d[1] = (__bf16)(w.y * scale);
        d[2] = (__bf16)(w.z * scale); d[3] = (__bf16)(w.w * scale);
        *(bf16x4*)(wlds + o * 256 + ((((g >> 1) ^ (o & 15)) << 4) | ((g & 1) * 8))) = d;
    }
    __syncthreads();

    bf16x8 xf[8];
    const float* xcol = x + (size_t)b * C_ * N_ + n;
    #pragma unroll
    for (int ch = 0; ch < 8; ++ch) {
        const int c0 = ch * 16 + 8 * h;
        bf16x8 v;
        #pragma unroll
        for (int e = 0; e < 8; ++e) v[e] = (__bf16)xcol[(size_t)(c0 + e) * N_];
        xf[ch] = v;
    }

    f32x16 acc[4];
    #pragma unroll
    for (int ob = 0; ob < 4; ++ob)
        #pragma unroll
        for (int rr = 0; rr < 16; ++rr) acc[ob][rr] = 0.0f;

    #pragma unroll
    for (int ch = 0; ch < 8; ++ch) {
        #pragma unroll
        for (int ob = 0; ob < 4; ++ob) {
            const char* wrow = wlds + (ob * 32 + col) * 256;
            bf16x8 wf = __builtin_bit_cast(bf16x8,
                *(const i32x4*)(wrow + (((ch * 2 + h) ^ (col & 15)) << 4)));
            acc[ob] = __builtin_amdgcn_mfma_f32_32x32x16_bf16(
                wf, xf[ch], acc[ob], 0, 0, 0);
        }
    }

    if (mat == 0) {
        unsigned short* dst = qT + (size_t)(b * N_ + n) * C_;
        #pragma unroll
        for (int ob = 0; ob < 4; ++ob) {
            #pragma unroll
            for (int qd = 0; qd < 4; ++qd) {
                const int obase = ob * 32 + 8 * qd + 4 * h;
                bf16x4 d;
                d[0] = (__bf16)(acc[ob][4 * qd + 0] + bias[obase + 0] * scale);
                d[1] = (__bf16)(acc[ob][4 * qd + 1] + bias[obase + 1] * scale);
                d[2] = (__bf16)(acc[ob][4 * qd + 2] + bias[obase + 2] * scale);
                d[3] = (__bf16)(acc[ob][4 * qd + 3] + bias[obase + 3] * scale);
                *(bf16x4*)(dst + obase) = d;
            }
        }
    } else if (mat == 1) {
        const int kt = (nb & 1) * 32 + col;               // key within 64-tile
        char* dst = kQ + (size_t)b * KB_PER_B + (size_t)(nb >> 1) * 16384 + kt * 256;
        const int kx = kt & 15;
        #pragma unroll
        for (int ob = 0; ob < 4; ++ob) {
            #pragma unroll
            for (int qd = 0; qd < 4; ++qd) {
                const int obase = ob * 32 + 8 * qd + 4 * h;
                bf16x4 d;
                d[0] = (__bf16)(acc[ob][4 * qd + 0] + bias[obase + 0]);
                d[1] = (__bf16)(acc[ob][4 * qd + 1] + bias[obase + 1]);
                d[2] = (__bf16)(acc[ob][4 * qd + 2] + bias[obase + 2]);
                d[3] = (__bf16)(acc[ob][4 * qd + 3] + bias[obase + 3]);
                *(bf16x4*)(dst + ((((ob * 4 + qd) ^ kx) << 4) | (8 * h))) = d;
            }
        }
    } else {
        char* dst = vQ + (size_t)b * KB_PER_B + (size_t)(nb >> 1) * 16384;
        const int kt  = (nb & 1) * 32 + col;
        const int m   = kt >> 4;
        const int w16 = kt & 15;
        const int hk  = (w16 >> 2) & 1;
        const int pos = (w16 & 3) | (((w16 >> 3) & 1) << 2);   // M2 element index
        #pragma unroll
        for (int ob = 0; ob < 4; ++ob) {
            #pragma unroll
            for (int rr = 0; rr < 16; ++rr) {
                const int o = ob * 32 + (rr & 3) + 8 * (rr >> 2) + 4 * h;
                const int R = o >> 1;
                const int cidx = (o & 1) * 8 + 2 * m + hk;
                *(unsigned short*)(dst + R * 256 + (((cidx ^ (R & 15)) << 4)) + pos * 2) =
                    __builtin_bit_cast(unsigned short,
                                       (__bf16)(acc[ob][rr] + bias[o]));
            }
        }
    }
}

// ---------------- flash attention over N/NS keys per WG ----------------
// grid = B * (N/128) * NS WGs x 256 thr. 4 waves = 4 q-blocks (128 q) all
// sharing one 64-key tile stream. Double-buffered LDS, 1 barrier/tile.
// FIXED-SHIFT softmax: p = exp2(e). QK uses 4 independent MFMA chains.
template<int NS>
__global__ __launch_bounds__(256, 2) void attn_kernel(
    const unsigned short* __restrict__ qT,
    const char* __restrict__ kQ,
    const char* __restrict__ vQ,
    unsigned short* __restrict__ pO,  // [NS][B][C][N] bf16 (un-normalized)
    float* __restrict__ lG)           // [NS][B][N] denominators
{
    __shared__ __align__(16) char smem[65536];   // 2 x (K 16KB | V 16KB)

    const int tid  = threadIdx.x;
    const int w    = tid >> 6;
    const int lane = tid & 63;
    const int l31  = lane & 31;
    const int h    = lane >> 5;

    const int orig = blockIdx.x;
    const int b    = (orig & 7) >> 1;                  // XCD-pair per batch
    const int idx  = ((orig >> 3) << 1) | (orig & 1);
    const int part = idx % NS;
    const int qg   = idx / NS;                         // 0..31
    const int i0   = qg * 128 + w * 32;

    const int NT = N_ / (NS * 64);                     // 64-key tiles per WG
    const char* kq0 = kQ + (size_t)b * KB_PER_B + (size_t)(part * NT) * 16384;
    const char* vq0 = vQ + (size_t)b * KB_PER_B + (size_t)(part * NT) * 16384;

    // Q fragments: element e of chunk ch <-> c = ch*16 + 8h + e
    bf16x8 qf[8];
    {
        const unsigned short* qrow = qT + (size_t)(b * N_ + i0 + l31) * C_;
        #pragma unroll
        for (int ch = 0; ch < 8; ++ch)
            qf[ch] = __builtin_bit_cast(bf16x8, *(const i32x4*)(qrow + ch * 16 + 8 * h));
    }
    bf16x8 ones;
    #pragma unroll
    for (int e = 0; e < 8; ++e) ones[e] = (__bf16)1.0f;

    f32x16 accO[4];
    #pragma unroll
    for (int cb = 0; cb < 4; ++cb)
        #pragma unroll
        for (int rr = 0; rr < 16; ++rr) accO[cb][rr] = 0.0f;
    f32x16 ls;                                        // P row-sum accumulator
    #pragma unroll
    for (int rr = 0; rr < 16; ++rr) ls[rr] = 0.0f;

    // staging: wave w copies bytes [w*8KB, w*8KB+8KB) of the 32KB tile image
    const int lane16 = lane * 16;
    auto stage = [&](int t, char* buf) {
        const char* g = ((w < 2) ? kq0 : vq0) + (size_t)t * 16384 + (w & 1) * 8192 + lane16;
        char* d = buf + (w >> 1) * 16384 + (w & 1) * 8192;
        #pragma unroll
        for (int u = 0; u < 8; ++u)
            stage16(g + u * 1024, d + u * 1024, lane16);
    };

    stage(0, smem);
    __syncthreads();
    int cur = 0;

    #pragma unroll 1
    for (int t = 0; t < NT; ++t) {
        char* kb = smem + cur * 32768;
        char* vb = kb + 16384;
        if (t + 1 < NT) stage(t + 1, smem + (cur ^ 1) * 32768);   // prefetch

        // ---- E^T[j][i] = sum_c K[c,j] Q[c,i], 4 independent chains ----
        f32x16 e0a, e0b, e1a, e1b;
        #pragma unroll
        for (int rr = 0; rr < 16; ++rr) {
            e0a[rr] = 0.0f; e0b[rr] = 0.0f; e1a[rr] = 0.0f; e1b[rr] = 0.0f;
        }
        {
            const char* kr0 = kb + l31 * 256;
            const int   kx  = l31 & 15;
            __builtin_amdgcn_s_setprio(1);
            #pragma unroll
            for (int ch = 0; ch < 8; ch += 2) {
                const int offa = ((2 * ch + h) ^ kx) << 4;
                const int offb = ((2 * (ch + 1) + h) ^ kx) << 4;
                bf16x8 k0a = __builtin_bit_cast(bf16x8, *(const i32x4*)(kr0 + offa));
                e0a = __builtin_amdgcn_mfma_f32_32x32x16_bf16(k0a, qf[ch], e0a, 0, 0, 0);
                bf16x8 k0b = __builtin_bit_cast(bf16x8, *(const i32x4*)(kr0 + offb));
                e0b = __builtin_amdgcn_mfma_f32_32x32x16_bf16(k0b, qf[ch + 1], e0b, 0, 0, 0);
                bf16x8 k1a = __builtin_bit_cast(bf16x8, *(const i32x4*)(kr0 + 8192 + offa));
                e1a = __builtin_amdgcn_mfma_f32_32x32x16_bf16(k1a, qf[ch], e1a, 0, 0, 0);
                bf16x8 k1b = __builtin_bit_cast(bf16x8, *(const i32x4*)(kr0 + 8192 + offb));
                e1b = __builtin_amdgcn_mfma_f32_32x32x16_bf16(k1b, qf[ch + 1], e1b, 0, 0, 0);
            }
            __builtin_amdgcn_s_setprio(0);
        }

        // ---- fixed-shift softmax numerators: p = exp2(e0a+e0b) ----
        f32x16 e0, e1;
        #pragma unroll
        for (int rr = 0; rr < 16; ++rr) {
            e0[rr] = exp2f(e0a[rr] + e0b[rr]);
            e1[rr] = exp2f(e1a[rr] + e1b[rr]);
        }

        // pack P: frag m element e <-> key 16m + (e&3) + 4h + 8*(e>>2)
        bf16x8 pf[4];
        #pragma unroll
        for (int m = 0; m < 4; ++m) {
            bf16x8 p;
            #pragma unroll
            for (int e = 0; e < 8; ++e)
                p[e] = (__bf16)((m < 2) ? e0[(m & 1) * 8 + e] : e1[(m & 1) * 8 + e]);
            pf[m] = p;
        }

        // ---- l += 1^T P (matrix pipe) ; accO += V P ----
        __builtin_amdgcn_s_setprio(1);
        #pragma unroll
        for (int m = 0; m < 4; ++m)
            ls = __builtin_amdgcn_mfma_f32_32x32x16_bf16(ones, pf[m], ls, 0, 0, 0);
        {
            const int rsw = l31 >> 1;          // (R & 15)
            const int ci  = (l31 & 1) * 8;
            #pragma unroll
            for (int cb = 0; cb < 4; ++cb) {
                const char* vrow = vb + (cb * 16 + (l31 >> 1)) * 256;
                #pragma unroll
                for (int m = 0; m < 4; ++m) {
                    bf16x8 vf = __builtin_bit_cast(bf16x8,
                        *(const i32x4*)(vrow + (((ci + 2 * m + h) ^ rsw) << 4)));
                    accO[cb] = __builtin_amdgcn_mfma_f32_32x32x16_bf16(
                        vf, pf[m], accO[cb], 0, 0, 0);
                }
            }
        }
        __builtin_amdgcn_s_setprio(0);

        __syncthreads();          // drains DMA (t+1 ready) + readers done
        cur ^= 1;
    }

    // ---- epilogue: un-normalized partial O (bf16) + denominator ----
    if (h == 0)
        lG[((size_t)part * B_ + b) * N_ + i0 + l31] = ls[0];

    unsigned short* pOq = pO + ((size_t)part * B_ + b) * C_ * N_;
    #pragma unroll
    for (int cb = 0; cb < 4; ++cb) {
        #pragma unroll
        for (int rr = 0; rr < 16; ++rr) {
            const int c = cb * 32 + (rr & 3) + 8 * (rr >> 2) + 4 * h;
            pOq[(size_t)c * N_ + i0 + l31] =
                __builtin_bit_cast(unsigned short, (__bf16)accO[cb][rr]);
        }
    }
}

// ---------------- merge NS key-range partials + residual ----------------
// Same fixed shift everywhere => merge is a plain sum.
template<int NS>
__global__ __launch_bounds__(256) void merge_kernel(
    const float* __restrict__ x,
    const unsigned short* __restrict__ pO,   // [NS][B][C][N] bf16
    const float* __restrict__ lG,            // [NS][B][N]
    float* __restrict__ out)
{
    const int idx = blockIdx.x * 256 + threadIdx.x;   // over B*C*N/4
    const int nq  = idx & (N_ / 4 - 1);
    const int bc  = idx >> 10;                        // b*C + c
    const int b   = bc >> 7;
    const size_t off = (size_t)bc * N_ + nq * 4;

    float4 xv = *(const float4*)(x + off);

    float num[4] = {0, 0, 0, 0}, den[4] = {0, 0, 0, 0};
    #pragma unroll
    for (int q = 0; q < NS; ++q) {
        bf16x4 r = *(const bf16x4*)(pO + (size_t)q * B_ * C_ * N_ + off);
        const float* lp = lG + ((size_t)q * B_ + b) * N_ + nq * 4;
        #pragma unroll
        for (int j = 0; j < 4; ++j) {
            num[j] += (float)r[j];
            den[j] += lp[j];
        }
    }
    float4 ov;
    ov.x = xv.x + num[0] / den[0];
    ov.y = xv.y + num[1] / den[1];
    ov.z = xv.z + num[2] / den[2];
    ov.w = xv.w + num[3] / den[3];
    *(float4*)(out + off) = ov;
}

extern "C" void kernel_launch(void* const* d_in, const int* in_sizes, int n_in,
                              void* d_out, int out_size, void* d_ws, size_t ws_size,
                              hipStream_t stream)
{
    const float* x  = (const float*)d_in[0];
    const float* Wq = (const float*)d_in[1];
    const float* bq = (const float*)d_in[2];
    const float* Wk = (const float*)d_in[3];
    const float* bk = (const float*)d_in[4];
    const float* Wv = (const float*)d_in[5];
    const float* bv = (const float*)d_in[6];
    float* out = (float*)d_out;

    unsigned short* qT = (unsigned short*)d_ws;              // 4 MiB
    char* kQ = (char*)(qT + (size_t)B_ * N_ * C_);           // 4 MiB
    char* vQ = kQ + (size_t)B_ * KB_PER_B;                   // 4 MiB
    unsigned short* pO = (unsigned short*)(vQ + (size_t)B_ * KB_PER_B);

    const size_t slotO = (size_t)B_ * C_ * N_;               // bf16 elems / slot
    const size_t slotL = (size_t)B_ * N_;                    // floats / slot
    const size_t base  = 3ull * B_ * N_ * C_ * 2;
    const size_t need4 = base + 4 * (slotO * 2 + slotL * 4);
    const int nMerge = (B_ * C_ * N_ / 4) / 256;

    proj_kernel<<<384, 256, 0, stream>>>(x, Wq, bq, Wk, bk, Wv, bv, qT, kQ, vQ);

    if (ws_size >= need4) {
        float* lG = (float*)(pO + 4 * slotO);
        attn_kernel<4><<<B_ * (N_ / 128) * 4, 256, 0, stream>>>(qT, kQ, vQ, pO, lG);
        merge_kernel<4><<<nMerge, 256, 0, stream>>>(x, pO, lG, out);
    } else {
        float* lG = (float*)(pO + 2 * slotO);
        attn_kernel<2><<<B_ * (N_ / 128) * 2, 256, 0, stream>>>(qT, kQ, vQ, pO, lG);
        merge_kernel<2><<<nMerge, 256, 0, stream>>>(x, pO, lG, out);
    }
}

// Round 12
// 66.707 us; speedup vs baseline: 1.0611x; 1.0003x over previous
//
#include <hip/hip_runtime.h>

#define B_ 4
#define C_ 128
#define N_ 4096
#define LOG2E 1.44269504088896340736f
#define KB_PER_B (C_ * N_ * 2)          // 1 MiB per batch for kQ / vQ

typedef __bf16 bf16x8 __attribute__((ext_vector_type(8)));
typedef __bf16 bf16x4 __attribute__((ext_vector_type(4)));
typedef float  f32x16 __attribute__((ext_vector_type(16)));
typedef int    i32x4  __attribute__((ext_vector_type(4)));

// 16B global -> LDS DMA. LDS dest = wave-uniform base + lane*16.
static __device__ __forceinline__ void stage16(const void* g_lane, char* lds_base, int lane16) {
#if __has_builtin(__builtin_amdgcn_global_load_lds)
    __builtin_amdgcn_global_load_lds(
        (const __attribute__((address_space(1))) void*)g_lane,
        (__attribute__((address_space(3))) void*)lds_base, 16, 0, 0);
    (void)lane16;
#else
    *(i32x4*)(lds_base + lane16) = *(const i32x4*)g_lane;
#endif
}

// ---------------- projection: q/k/v = W @ x + b (1x1 conv) -------------
// qT [B][N][C] bf16 (q scaled by log2e).
// kQ [B][tile64][j 64][chunk16B ^ (j&15)]          (16 KB / 64-key tile)
// vQ [B][tile64][R=c>>1 64][chunk16B ^ (R&15)]     (16 KB / 64-key tile)
//    chunkIdx = (c&1)*8 + 2m + hk; within-chunk M2 key order.
__global__ __launch_bounds__(256) void proj_kernel(
    const float* __restrict__ x,
    const float* __restrict__ Wq, const float* __restrict__ bq,
    const float* __restrict__ Wk, const float* __restrict__ bk,
    const float* __restrict__ Wv, const float* __restrict__ bv,
    unsigned short* __restrict__ qT, char* __restrict__ kQ,
    char* __restrict__ vQ)
{
    __shared__ __align__(16) char wlds[32768];   // W bf16, swizzled rows (256B)

    const int tid  = threadIdx.x;
    const int wave = tid >> 6;
    const int lane = tid & 63;
    const int col  = lane & 31;
    const int h    = lane >> 5;

    const int jw  = blockIdx.x * 4 + wave;   // 0..1535 = mat*512 + b*128 + nb
    const int mat = jw >> 9;                 // uniform per WG
    const int rem = jw & 511;
    const int b   = rem >> 7;
    const int nb  = rem & 127;
    const int n   = nb * 32 + col;

    const float* W    = (mat == 0) ? Wq : (mat == 1) ? Wk : Wv;
    const float* bias = (mat == 0) ? bq : (mat == 1) ? bk : bv;
    const float  scale = (mat == 0) ? LOG2E : 1.0f;

    #pragma unroll
    for (int k = 0; k < 16; ++k) {
        const int q = tid + k * 256;          // quad index, 4 floats each
        const int o = q >> 5;                 // W row (output channel)
        const int g = q & 31;                 // 8B granule within row
        float4 w = *((const float4*)W + q);
        bf16x4 d;
        d[0] = (__bf16)(w.x * scale); d[1] = (__bf16)(w.y * scale);
        d[2] = (__bf16)(w.z * scale); d[3] = (__bf16)(w.w * scale);
        *(bf16x4*)(wlds + o * 256 + ((((g >> 1) ^ (o & 15)) << 4) | ((g & 1) * 8))) = d;
    }
    __syncthreads();

    bf16x8 xf[8];
    const float* xcol = x + (size_t)b * C_ * N_ + n;
    #pragma unroll
    for (int ch = 0; ch < 8; ++ch) {
        const int c0 = ch * 16 + 8 * h;
        bf16x8 v;
        #pragma unroll
        for (int e = 0; e < 8; ++e) v[e] = (__bf16)xcol[(size_t)(c0 + e) * N_];
        xf[ch] = v;
    }

    f32x16 acc[4];
    #pragma unroll
    for (int ob = 0; ob < 4; ++ob)
        #pragma unroll
        for (int rr = 0; rr < 16; ++rr) acc[ob][rr] = 0.0f;

    #pragma unroll
    for (int ch = 0; ch < 8; ++ch) {
        #pragma unroll
        for (int ob = 0; ob < 4; ++ob) {
            const char* wrow = wlds + (ob * 32 + col) * 256;
            bf16x8 wf = __builtin_bit_cast(bf16x8,
                *(const i32x4*)(wrow + (((ch * 2 + h) ^ (col & 15)) << 4)));
            acc[ob] = __builtin_amdgcn_mfma_f32_32x32x16_bf16(
                wf, xf[ch], acc[ob], 0, 0, 0);
        }
    }

    if (mat == 0) {
        unsigned short* dst = qT + (size_t)(b * N_ + n) * C_;
        #pragma unroll
        for (int ob = 0; ob < 4; ++ob) {
            #pragma unroll
            for (int qd = 0; qd < 4; ++qd) {
                const int obase = ob * 32 + 8 * qd + 4 * h;
                bf16x4 d;
                d[0] = (__bf16)(acc[ob][4 * qd + 0] + bias[obase + 0] * scale);
                d[1] = (__bf16)(acc[ob][4 * qd + 1] + bias[obase + 1] * scale);
                d[2] = (__bf16)(acc[ob][4 * qd + 2] + bias[obase + 2] * scale);
                d[3] = (__bf16)(acc[ob][4 * qd + 3] + bias[obase + 3] * scale);
                *(bf16x4*)(dst + obase) = d;
            }
        }
    } else if (mat == 1) {
        const int kt = (nb & 1) * 32 + col;               // key within 64-tile
        char* dst = kQ + (size_t)b * KB_PER_B + (size_t)(nb >> 1) * 16384 + kt * 256;
        const int kx = kt & 15;
        #pragma unroll
        for (int ob = 0; ob < 4; ++ob) {
            #pragma unroll
            for (int qd = 0; qd < 4; ++qd) {
                const int obase = ob * 32 + 8 * qd + 4 * h;
                bf16x4 d;
                d[0] = (__bf16)(acc[ob][4 * qd + 0] + bias[obase + 0]);
                d[1] = (__bf16)(acc[ob][4 * qd + 1] + bias[obase + 1]);
                d[2] = (__bf16)(acc[ob][4 * qd + 2] + bias[obase + 2]);
                d[3] = (__bf16)(acc[ob][4 * qd + 3] + bias[obase + 3]);
                *(bf16x4*)(dst + ((((ob * 4 + qd) ^ kx) << 4) | (8 * h))) = d;
            }
        }
    } else {
        char* dst = vQ + (size_t)b * KB_PER_B + (size_t)(nb >> 1) * 16384;
        const int kt  = (nb & 1) * 32 + col;
        const int m   = kt >> 4;
        const int w16 = kt & 15;
        const int hk  = (w16 >> 2) & 1;
        const int pos = (w16 & 3) | (((w16 >> 3) & 1) << 2);   // M2 element index
        #pragma unroll
        for (int ob = 0; ob < 4; ++ob) {
            #pragma unroll
            for (int rr = 0; rr < 16; ++rr) {
                const int o = ob * 32 + (rr & 3) + 8 * (rr >> 2) + 4 * h;
                const int R = o >> 1;
                const int cidx = (o & 1) * 8 + 2 * m + hk;
                *(unsigned short*)(dst + R * 256 + (((cidx ^ (R & 15)) << 4)) + pos * 2) =
                    __builtin_bit_cast(unsigned short,
                                       (__bf16)(acc[ob][rr] + bias[o]));
            }
        }
    }
}

// ---------------- flash attention over N/NS keys per WG ----------------
// grid = B * (N/128) * NS WGs x 256 thr. 4 waves = 4 q-blocks (128 q) all
// sharing one 64-key tile stream. Double-buffered LDS, 1 barrier/tile.
// SOFTWARE PIPELINE (T15): iter t runs QK(t) || {exp,pack,PV}(t-1), so the
// matrix pipe gets two independent MFMA streams and VALU overlaps both.
// FIXED-SHIFT softmax: p = exp2(e) (shift-invariant; merged exactly later).
template<int NS>
__global__ __launch_bounds__(256, 2) void attn_kernel(
    const unsigned short* __restrict__ qT,
    const char* __restrict__ kQ,
    const char* __restrict__ vQ,
    unsigned short* __restrict__ pO,  // [NS][B][C][N] bf16 (un-normalized)
    float* __restrict__ lG)           // [NS][B][N] denominators
{
    __shared__ __align__(16) char smem[65536];   // K0|K1|V0|V1, 16 KB each

    const int tid  = threadIdx.x;
    const int w    = tid >> 6;
    const int lane = tid & 63;
    const int l31  = lane & 31;
    const int h    = lane >> 5;

    const int orig = blockIdx.x;
    const int b    = (orig & 7) >> 1;                  // XCD-pair per batch
    const int idx  = ((orig >> 3) << 1) | (orig & 1);
    const int part = idx % NS;
    const int qg   = idx / NS;                         // 0..31
    const int i0   = qg * 128 + w * 32;

    const int NT = N_ / (NS * 64);                     // 64-key tiles per WG
    const char* kq0 = kQ + (size_t)b * KB_PER_B + (size_t)(part * NT) * 16384;
    const char* vq0 = vQ + (size_t)b * KB_PER_B + (size_t)(part * NT) * 16384;
    char* kbufs = smem;                                // [2][16KB]
    char* vbufs = smem + 32768;                        // [2][16KB]

    // Q fragments: element e of chunk ch <-> c = ch*16 + 8h + e
    bf16x8 qf[8];
    {
        const unsigned short* qrow = qT + (size_t)(b * N_ + i0 + l31) * C_;
        #pragma unroll
        for (int ch = 0; ch < 8; ++ch)
            qf[ch] = __builtin_bit_cast(bf16x8, *(const i32x4*)(qrow + ch * 16 + 8 * h));
    }
    bf16x8 ones;
    #pragma unroll
    for (int e = 0; e < 8; ++e) ones[e] = (__bf16)1.0f;

    f32x16 accO[4];
    #pragma unroll
    for (int cb = 0; cb < 4; ++cb)
        #pragma unroll
        for (int rr = 0; rr < 16; ++rr) accO[cb][rr] = 0.0f;
    f32x16 ls;                                        // P row-sum accumulator
    #pragma unroll
    for (int rr = 0; rr < 16; ++rr) ls[rr] = 0.0f;

    // staging helpers: 4 waves cooperatively copy one 16 KB tile image
    const int lane16 = lane * 16;
    auto stageK = [&](int t, int buf) {
        const char* g = kq0 + (size_t)t * 16384 + w * 4096 + lane16;
        char* d = kbufs + buf * 16384 + w * 4096;
        #pragma unroll
        for (int u = 0; u < 4; ++u)
            stage16(g + u * 1024, d + u * 1024, lane16);
    };
    auto stageV = [&](int t, int buf) {
        const char* g = vq0 + (size_t)t * 16384 + w * 4096 + lane16;
        char* d = vbufs + buf * 16384 + w * 4096;
        #pragma unroll
        for (int u = 0; u < 4; ++u)
            stage16(g + u * 1024, d + u * 1024, lane16);
    };

    // QK for tile in kbuf[buf] -> (o0, o1)
    const int kx = l31 & 15;
    auto QK = [&](int buf, f32x16& o0, f32x16& o1) {
        const char* kr0 = kbufs + buf * 16384 + l31 * 256;
        #pragma unroll
        for (int rr = 0; rr < 16; ++rr) { o0[rr] = 0.0f; o1[rr] = 0.0f; }
        __builtin_amdgcn_s_setprio(1);
        #pragma unroll
        for (int ch = 0; ch < 8; ++ch) {
            const int off = ((2 * ch + h) ^ kx) << 4;
            bf16x8 k0 = __builtin_bit_cast(bf16x8, *(const i32x4*)(kr0 + off));
            o0 = __builtin_amdgcn_mfma_f32_32x32x16_bf16(k0, qf[ch], o0, 0, 0, 0);
            bf16x8 k1 = __builtin_bit_cast(bf16x8, *(const i32x4*)(kr0 + 8192 + off));
            o1 = __builtin_amdgcn_mfma_f32_32x32x16_bf16(k1, qf[ch], o1, 0, 0, 0);
        }
        __builtin_amdgcn_s_setprio(0);
    };

    // exp + pack + ls + PV for the saved tile (V in vbuf[buf])
    const int rsw = l31 >> 1;
    const int ci  = (l31 & 1) * 8;
    auto FIN = [&](int buf, const f32x16& s0, const f32x16& s1) {
        float p0[16], p1[16];
        #pragma unroll
        for (int rr = 0; rr < 16; ++rr) {
            p0[rr] = exp2f(s0[rr]);
            p1[rr] = exp2f(s1[rr]);
        }
        bf16x8 pf[4];
        #pragma unroll
        for (int m = 0; m < 4; ++m) {
            bf16x8 p;
            #pragma unroll
            for (int e = 0; e < 8; ++e)
                p[e] = (__bf16)((m < 2) ? p0[(m & 1) * 8 + e] : p1[(m & 1) * 8 + e]);
            pf[m] = p;
        }
        __builtin_amdgcn_s_setprio(1);
        #pragma unroll
        for (int m = 0; m < 4; ++m)
            ls = __builtin_amdgcn_mfma_f32_32x32x16_bf16(ones, pf[m], ls, 0, 0, 0);
        const char* vbase = vbufs + buf * 16384;
        #pragma unroll
        for (int cb = 0; cb < 4; ++cb) {
            const char* vrow = vbase + (cb * 16 + (l31 >> 1)) * 256;
            #pragma unroll
            for (int m = 0; m < 4; ++m) {
                bf16x8 vf = __builtin_bit_cast(bf16x8,
                    *(const i32x4*)(vrow + (((ci + 2 * m + h) ^ rsw) << 4)));
                accO[cb] = __builtin_amdgcn_mfma_f32_32x32x16_bf16(
                    vf, pf[m], accO[cb], 0, 0, 0);
            }
        }
        __builtin_amdgcn_s_setprio(0);
    };

    f32x16 s0, s1;          // QK output carried across one iteration

    // ---- prologue: tile 0 ----
    stageK(0, 0);
    __syncthreads();                       // K(0) ready
    stageK(1, 1);                          // K(1)
    stageV(0, 1);                          // V(0) -> vb[1] (read next iter)
    QK(0, s0, s1);
    __syncthreads();                       // K(1),V(0) ready
    int cur = 1;

    #pragma unroll 2
    for (int t = 1; t < NT; ++t) {
        // stage K(t+1) and V(t) into the buffers freed this iteration
        if (t + 1 < NT) stageK(t + 1, cur ^ 1);
        stageV(t, cur ^ 1);

        f32x16 e0, e1;
        QK(cur, e0, e1);                   // tile t      (matrix stream A)
        FIN(cur, s0, s1);                  // tile t-1    (VALU + stream B)
        s0 = e0; s1 = e1;

        __syncthreads();                   // staged tiles ready; readers done
        cur ^= 1;
    }

    // ---- epilogue: finish tile NT-1 (V staged into vb[cur]) ----
    FIN(cur, s0, s1);

    // ---- un-normalized partial O (bf16) + denominator ----
    if (h == 0)
        lG[((size_t)part * B_ + b) * N_ + i0 + l31] = ls[0];

    unsigned short* pOq = pO + ((size_t)part * B_ + b) * C_ * N_;
    #pragma unroll
    for (int cb = 0; cb < 4; ++cb) {
        #pragma unroll
        for (int rr = 0; rr < 16; ++rr) {
            const int c = cb * 32 + (rr & 3) + 8 * (rr >> 2) + 4 * h;
            pOq[(size_t)c * N_ + i0 + l31] =
                __builtin_bit_cast(unsigned short, (__bf16)accO[cb][rr]);
        }
    }
}

// ---------------- merge NS key-range partials + residual ----------------
// Same fixed shift everywhere => merge is a plain sum.
template<int NS>
__global__ __launch_bounds__(256) void merge_kernel(
    const float* __restrict__ x,
    const unsigned short* __restrict__ pO,   // [NS][B][C][N] bf16
    const float* __restrict__ lG,            // [NS][B][N]
    float* __restrict__ out)
{
    const int idx = blockIdx.x * 256 + threadIdx.x;   // over B*C*N/4
    const int nq  = idx & (N_ / 4 - 1);
    const int bc  = idx >> 10;                        // b*C + c
    const int b   = bc >> 7;
    const size_t off = (size_t)bc * N_ + nq * 4;

    float4 xv = *(const float4*)(x + off);

    float num[4] = {0, 0, 0, 0}, den[4] = {0, 0, 0, 0};
    #pragma unroll
    for (int q = 0; q < NS; ++q) {
        bf16x4 r = *(const bf16x4*)(pO + (size_t)q * B_ * C_ * N_ + off);
        const float* lp = lG + ((size_t)q * B_ + b) * N_ + nq * 4;
        #pragma unroll
        for (int j = 0; j < 4; ++j) {
            num[j] += (float)r[j];
            den[j] += lp[j];
        }
    }
    float4 ov;
    ov.x = xv.x + num[0] / den[0];
    ov.y = xv.y + num[1] / den[1];
    ov.z = xv.z + num[2] / den[2];
    ov.w = xv.w + num[3] / den[3];
    *(float4*)(out + off) = ov;
}

extern "C" void kernel_launch(void* const* d_in, const int* in_sizes, int n_in,
                              void* d_out, int out_size, void* d_ws, size_t ws_size,
                              hipStream_t stream)
{
    const float* x  = (const float*)d_in[0];
    const float* Wq = (const float*)d_in[1];
    const float* bq = (const float*)d_in[2];
    const float* Wk = (const float*)d_in[3];
    const float* bk = (const float*)d_in[4];
    const float* Wv = (const float*)d_in[5];
    const float* bv = (const float*)d_in[6];
    float* out = (float*)d_out;

    unsigned short* qT = (unsigned short*)d_ws;              // 4 MiB
    char* kQ = (char*)(qT + (size_t)B_ * N_ * C_);           // 4 MiB
    char* vQ = kQ + (size_t)B_ * KB_PER_B;                   // 4 MiB
    unsigned short* pO = (unsigned short*)(vQ + (size_t)B_ * KB_PER_B);

    const size_t slotO = (size_t)B_ * C_ * N_;               // bf16 elems / slot
    const size_t slotL = (size_t)B_ * N_;                    // floats / slot
    const size_t base  = 3ull * B_ * N_ * C_ * 2;
    const size_t need4 = base + 4 * (slotO * 2 + slotL * 4);
    const int nMerge = (B_ * C_ * N_ / 4) / 256;

    proj_kernel<<<384, 256, 0, stream>>>(x, Wq, bq, Wk, bk, Wv, bv, qT, kQ, vQ);

    if (ws_size >= need4) {
        float* lG = (float*)(pO + 4 * slotO);
        attn_kernel<4><<<B_ * (N_ / 128) * 4, 256, 0, stream>>>(qT, kQ, vQ, pO, lG);
        merge_kernel<4><<<nMerge, 256, 0, stream>>>(x, pO, lG, out);
    } else {
        float* lG = (float*)(pO + 2 * slotO);
        attn_kernel<2><<<B_ * (N_ / 128) * 2, 256, 0, stream>>>(qT, kQ, vQ, pO, lG);
        merge_kernel<2><<<nMerge, 256, 0, stream>>>(x, pO, lG, out);
    }
}